// Round 2
// baseline (3793.142 us; speedup 1.0000x reference)
//
#include <hip/hip_runtime.h>
#include <float.h>

// VQ-VAE codebook assignment, fp32-grid-faithful argmin.
// Pass A: fp32 distances + per-row top-2; Pass B: flagged rows (gap<=MARGIN)
// re-checked with exact fp64 dots -> exact fp32-grid lexicographic argmin.
// z:   [16, 256, 32, 32] fp32   (M = 16384 rows, K = 256)
// emb: [8192, 256] fp32         (N = 8192 codes)
// out: [quantized 4194304][st 4194304][indices-as-float 16384]

#define KDIM 256
#define NCODES 8192
#define MTOTAL 16384
#define MT 64
#define NT 64
#define NTILES (NCODES / NT)
#define ST_OFF 4194304
#define IDX_OFF 8388608
#define MARGIN 4e-5f   // > max cell width (3.05e-5 for d<512) + 2*fp32 accum err

// LDS layout: [row][256] floats, XOR quad-swizzle so column-slice reads hit
// 8 distinct bank-quads (b128 BW floor). element index:
__device__ __forceinline__ int swz(int row, int k) {
    return (row << 8) + ((((k >> 2) ^ (row & 7)) << 2) | (k & 3));
}
__device__ __forceinline__ const float4* vptr(const float* base, int row, int kq) {
    return reinterpret_cast<const float4*>(base + (row << 8) + (((kq ^ (row & 7)) << 2)));
}

__global__ __launch_bounds__(256, 1) void vq_kernel(
    const float* __restrict__ z, const float* __restrict__ emb,
    float* __restrict__ out)
{
    __shared__ float zT[MT * KDIM];      // 64 KB
    __shared__ float es[NT * KDIM];      // 64 KB
    __shared__ float z2s[MT];
    __shared__ float b1d_s[MT][16];
    __shared__ int   b1n_s[MT][16];
    __shared__ float b2d_s[MT][16];
    __shared__ float part[NT][4][8];     // pass-B partial dots
    __shared__ float best_s[MT];
    __shared__ int   bestn_s[MT];
    __shared__ int   flaglist[MT];
    __shared__ unsigned long long packed_s[MT];
    __shared__ int   nflag;
    __shared__ int   idx_s[MT];

    const int tid  = threadIdx.x;
    const int m0   = blockIdx.x * MT;
    const int nimg = m0 >> 10;
    const int hw0  = m0 & 1023;

    // ---- stage z transposed: zT[r][k] = z[nimg, k, hw0+r] (swizzled)
    {
        const int l = tid & 63, w = tid >> 6;
        const float* zb = z + (size_t)nimg * (KDIM * 1024) + hw0 + l;
        #pragma unroll 8
        for (int i = 0; i < 64; ++i) {
            const int k = (w << 6) + i;
            zT[swz(l, k)] = zb[(size_t)k * 1024];   // coalesced along l
        }
    }
    if (tid == 0) nflag = 0;
    __syncthreads();

    // ---- ||z||^2 per row (fp64->fp32; row-constant offset vs numpy is an
    //      exact grid translation -> argmin-invariant, verified round 1)
    if (tid < MT) {
        double s = 0.0;
        for (int k = 0; k < KDIM; ++k) { const double v = (double)zT[swz(tid, k)]; s = fma(v, v, s); }
        z2s[tid] = (float)s;
        packed_s[tid] = ~0ull;
    }
    __syncthreads();

    const int g = tid >> 4;   // row group: rows 4g..4g+3
    const int h = tid & 15;   // col group: codes 4h..4h+3 in tile

    float z2r[4];
    #pragma unroll
    for (int i = 0; i < 4; ++i) z2r[i] = z2s[4 * g + i];

    float b1d[4], b2d[4]; int b1n[4];
    #pragma unroll
    for (int i = 0; i < 4; ++i) { b1d[i] = FLT_MAX; b2d[i] = FLT_MAX; b1n[i] = 0; }

    // ================= PASS A: fp32 distances, top-2 tracking =================
    for (int nt = 0; nt < NTILES; ++nt) {
        const int n0 = nt * NT;
        __syncthreads();
        {   // stage emb tile: es[nn][k=tid] (swizzled), coalesced along tid
            const float* eb = emb + (size_t)n0 * KDIM + tid;
            #pragma unroll 8
            for (int nn = 0; nn < NT; ++nn)
                es[swz(nn, tid)] = eb[(size_t)nn * KDIM];
        }
        __syncthreads();

        float acc[4][4];
        #pragma unroll
        for (int i = 0; i < 4; ++i)
            #pragma unroll
            for (int j = 0; j < 4; ++j) acc[i][j] = 0.f;

        #pragma unroll 2
        for (int kq = 0; kq < 64; ++kq) {
            float4 zq[4], eq[4];
            #pragma unroll
            for (int i = 0; i < 4; ++i) zq[i] = *vptr(zT, 4 * g + i, kq);
            #pragma unroll
            for (int j = 0; j < 4; ++j) eq[j] = *vptr(es, 4 * h + j, kq);
            #pragma unroll
            for (int i = 0; i < 4; ++i)
                #pragma unroll
                for (int j = 0; j < 4; ++j) {
                    acc[i][j] = fmaf(zq[i].x, eq[j].x, acc[i][j]);
                    acc[i][j] = fmaf(zq[i].y, eq[j].y, acc[i][j]);
                    acc[i][j] = fmaf(zq[i].z, eq[j].z, acc[i][j]);
                    acc[i][j] = fmaf(zq[i].w, eq[j].w, acc[i][j]);
                }
        }

        #pragma unroll
        for (int j = 0; j < 4; ++j) {
            const int n = n0 + 4 * h + j;          // ascending n scan
            #pragma unroll
            for (int i = 0; i < 4; ++i) {
                const float d = z2r[i] - 2.f * acc[i][j];
                if (d < b1d[i]) { b2d[i] = b1d[i]; b1d[i] = d; b1n[i] = n; }
                else            b2d[i] = fminf(b2d[i], d);
            }
        }
    }

    // ---- top-2 merge across the 16 col-groups, lexicographic (d, n)
    #pragma unroll
    for (int i = 0; i < 4; ++i) {
        b1d_s[4 * g + i][h] = b1d[i]; b1n_s[4 * g + i][h] = b1n[i]; b2d_s[4 * g + i][h] = b2d[i];
    }
    __syncthreads();

    if (tid < MT) {
        float B1 = b1d_s[tid][0]; int N1 = b1n_s[tid][0]; float B2 = b2d_s[tid][0];
        for (int t = 1; t < 16; ++t) {
            const float c1 = b1d_s[tid][t]; const int cn = b1n_s[tid][t]; const float c2 = b2d_s[tid][t];
            if (c1 < B1 || (c1 == B1 && cn < N1)) { B2 = fminf(B1, c2); B1 = c1; N1 = cn; }
            else B2 = fminf(B2, c1);
        }
        best_s[tid] = B1; bestn_s[tid] = N1;
        if (B2 - B1 <= MARGIN) { const int fi = atomicAdd(&nflag, 1); flaglist[fi] = tid; }
    }
    __syncthreads();

    // ================= PASS B: exact resolution of flagged rows ==============
    const int NF = nflag;
    if (NF > 0) {
        const int nn = tid & 63, q = tid >> 6;
        for (int f0 = 0; f0 < NF; f0 += 8) {
            int rloc[8];
            #pragma unroll
            for (int f = 0; f < 8; ++f) {
                const int fi = f0 + f;
                rloc[f] = flaglist[fi < NF ? fi : (NF - 1)];
            }
            for (int nt = 0; nt < NTILES; ++nt) {
                const int n0 = nt * NT;
                __syncthreads();
                {   // restage emb tile
                    const float* eb = emb + (size_t)n0 * KDIM + tid;
                    #pragma unroll 8
                    for (int m = 0; m < NT; ++m)
                        es[swz(m, tid)] = eb[(size_t)m * KDIM];
                }
                __syncthreads();

                float p[8];
                #pragma unroll
                for (int f = 0; f < 8; ++f) p[f] = 0.f;
                for (int kk = 0; kk < 16; ++kk) {
                    const int kq = (q << 4) + kk;
                    const float4 ev = *vptr(es, nn, kq);
                    #pragma unroll
                    for (int f = 0; f < 8; ++f) {
                        const float4 zv = *vptr(zT, rloc[f], kq);  // broadcast
                        p[f] = fmaf(zv.x, ev.x, p[f]);
                        p[f] = fmaf(zv.y, ev.y, p[f]);
                        p[f] = fmaf(zv.z, ev.z, p[f]);
                        p[f] = fmaf(zv.w, ev.w, p[f]);
                    }
                }
                #pragma unroll
                for (int f = 0; f < 8; ++f) part[nn][q][f] = p[f];
                __syncthreads();

                if (tid < NT) {
                    #pragma unroll
                    for (int f = 0; f < 8; ++f) {
                        if (f0 + f < NF) {
                            const int r = rloc[f];
                            const float dot = ((part[tid][0][f] + part[tid][1][f])
                                               + part[tid][2][f]) + part[tid][3][f];
                            const float d = z2s[r] - 2.f * dot;
                            if (d <= best_s[r] + MARGIN) {
                                // exact fp64 dot -> exact fp32-grid distance
                                double dd = 0.0;
                                for (int k = 0; k < KDIM; ++k)
                                    dd = fma((double)zT[swz(r, k)], (double)es[swz(tid, k)], dd);
                                const float dg = z2s[r] - 2.f * (float)dd;
                                const unsigned long long key =
                                    ((unsigned long long)__float_as_uint(dg) << 32)
                                    | (unsigned long long)(unsigned)(n0 + tid);
                                atomicMin(&packed_s[r], key);
                            }
                        }
                    }
                }
            }
        }
    }
    __syncthreads();

    // ---- final index per row
    if (tid < MT) {
        int n = bestn_s[tid];
        if (packed_s[tid] != ~0ull) n = (int)(packed_s[tid] & 0xFFFFFFFFull);
        idx_s[tid] = n;
        out[IDX_OFF + m0 + tid] = (float)n;
    }
    __syncthreads();

    // ---- gather emb[best] -> quantized + st (coalesced along hw)
    const int r  = tid & 63;
    const int c0 = tid >> 6;
    const float* erow = emb + (size_t)idx_s[r] * KDIM;
    const size_t obase = (size_t)nimg * 262144 + hw0 + r;
    for (int c = c0; c < KDIM; c += 4) {
        const float qv = erow[c];
        out[obase + (size_t)c * 1024] = qv;
        out[ST_OFF + obase + (size_t)c * 1024] = qv;
    }
}

extern "C" void kernel_launch(void* const* d_in, const int* in_sizes, int n_in,
                              void* d_out, int out_size, void* d_ws, size_t ws_size,
                              hipStream_t stream) {
    const float* zp   = (const float*)d_in[0];
    const float* embp = (const float*)d_in[1];
    float* outp = (float*)d_out;
    vq_kernel<<<MTOTAL / MT, 256, 0, stream>>>(zp, embp, outp);
}

// Round 3
// 1963.443 us; speedup vs baseline: 1.9319x; 1.9319x over previous
//
#include <hip/hip_runtime.h>
#include <float.h>

// VQ-VAE codebook assignment, fp32-grid-faithful argmin.
// Pass A: fp32 distances, per-thread top-3 (d,n); flag rows with merged
// B2-B1 <= MARGIN. Pass B: candidates from recorded top-3 only (no emb
// re-stream), exact fp64 dot -> fp32-grid lexicographic (d,n) argmin.
// z:   [16, 256, 32, 32] fp32   (M = 16384 rows, K = 256)
// emb: [8192, 256] fp32         (N = 8192 codes)
// out: [quantized 4194304][st 4194304][indices-as-float 16384]

#define KDIM 256
#define NCODES 8192
#define MTOTAL 16384
#define MT 64
#define NT 64
#define NTILES (NCODES / NT)
#define ST_OFF 4194304
#define IDX_OFF 8388608
#define MARGIN 4e-5f     // > grid cell (3.05e-5 @ d<512) + 2x fp32 accum err
#define CANDCAP 1024

// Swizzle: rows are accessed at stride 4 (4g+i / 4h+j), so the XOR key must
// be (row>>2)&7 (the varying bits), NOT row&7 (round-2 bug: 8-way conflicts).
__device__ __forceinline__ int swz_idx(int row, int k) {
    return (row << 8) + ((((k >> 2) ^ ((row >> 2) & 7)) << 2) | (k & 3));
}

__global__ __launch_bounds__(256, 1) void vq_kernel(
    const float* __restrict__ z, const float* __restrict__ emb,
    float* __restrict__ out)
{
    __shared__ float zT[MT * KDIM];              // 64 KB, swizzled
    __shared__ float es[NT * KDIM];              // 64 KB, swizzled; overlaid after pass A
    __shared__ double z2part[MT][4];
    __shared__ float z2s[MT];
    __shared__ float best_s[MT];
    __shared__ int   bestn_s[MT];
    __shared__ unsigned long long packed_s[MT];
    __shared__ int   cand[CANDCAP];
    __shared__ int   candcnt;
    __shared__ int   idx_s[MT];

    // overlay on es after pass A: per-thread top-3 triples
    float* red_d = es;                           // [64 rows][16 threads][3]
    int*   red_n = (int*)(es + MT * 16 * 3);     // [64 rows][16 threads][3]

    const int tid  = threadIdx.x;
    const int m0   = blockIdx.x * MT;
    const int nimg = m0 >> 10;
    const int hw0  = m0 & 1023;

    // ---- stage z transposed: zT[r][k] = z[nimg, k, hw0+r] (swizzled)
    {
        const int l = tid & 63, w = tid >> 6;
        const float* zb = z + (size_t)nimg * (KDIM * 1024) + hw0 + l;
        #pragma unroll 8
        for (int i = 0; i < 64; ++i) {
            const int k = (w << 6) + i;
            zT[swz_idx(l, k)] = zb[(size_t)k * 1024];  // coalesced along l
        }
    }

    // ---- prefetch emb tile 0 into registers (T14 issue-early)
    // mapping: 8 lanes per row (quad-phase = tid&7) -> conflict-free b128
    // LDS writes AND 128B-contiguous coalesced global reads.
    const int srow = tid >> 3;     // 0..31
    const int sq   = tid & 7;
    float4 R[16];
    {
        #pragma unroll
        for (int p = 0; p < 2; ++p) {
            const int row = srow + 32 * p;
            const float4* eg = (const float4*)(emb + (size_t)row * KDIM);
            #pragma unroll
            for (int i = 0; i < 8; ++i) R[p * 8 + i] = eg[sq + 8 * i];
        }
    }
    __syncthreads();   // zT ready (also drains tile-0 loads; one-time cost)

    // ---- ||z||^2, 4 threads/row fp64 partials (any per-row constant is
    //      argmin-invariant: exact grid translation)
    {
        const int row = tid >> 2, ks = (tid & 3) << 6;
        double s = 0.0;
        for (int k = ks; k < ks + 64; ++k) {
            const double v = (double)zT[swz_idx(row, k)];
            s = fma(v, v, s);
        }
        z2part[row][tid & 3] = s;
    }
    if (tid == 0) candcnt = 0;
    __syncthreads();
    if (tid < MT) {
        z2s[tid] = (float)(((z2part[tid][0] + z2part[tid][1])
                            + z2part[tid][2]) + z2part[tid][3]);
        packed_s[tid] = ~0ull;
    }
    __syncthreads();

    const int g = tid >> 4;        // row group: rows 4g..4g+3
    const int h = tid & 15;        // col group: codes 4h..4h+3 in tile
    const int kz = g & 7;          // swizzle keys ((4g+i)>>2)&7 == g&7, const over i
    const int ke = h & 7;
    const float* zb4 = zT + ((4 * g) << 8);
    const float* eb4 = es + ((4 * h) << 8);

    float z2r[4];
    #pragma unroll
    for (int i = 0; i < 4; ++i) z2r[i] = z2s[4 * g + i];

    float b1d[4], b2d[4], b3d[4];
    int   n1[4], n2[4], n3[4];
    #pragma unroll
    for (int i = 0; i < 4; ++i) {
        b1d[i] = FLT_MAX; b2d[i] = FLT_MAX; b3d[i] = FLT_MAX;
        n1[i] = 0; n2[i] = 0; n3[i] = 0;
    }

    // ================= PASS A =================
    for (int nt = 0; nt < NTILES; ++nt) {
        __syncthreads();   // (A) prev-tile readers done; R loads landed
        {   // write R -> es (swizzled; conflict-free: 8 lanes/row hit 8 quads)
            #pragma unroll
            for (int p = 0; p < 2; ++p) {
                const int row = srow + 32 * p;
                const int key = (row >> 2) & 7;
                float* eb = es + (row << 8);
                #pragma unroll
                for (int i = 0; i < 8; ++i) {
                    const int q = sq + 8 * i;
                    *(float4*)(eb + ((q ^ key) << 2)) = R[p * 8 + i];
                }
            }
        }
        __syncthreads();   // (B) es ready (drains ds_writes; no vmem in flight)

        if (nt + 1 < NTILES) {   // issue next tile's loads; land during compute
            const int n0n = (nt + 1) * NT;
            #pragma unroll
            for (int p = 0; p < 2; ++p) {
                const int row = srow + 32 * p;
                const float4* eg = (const float4*)(emb + (size_t)(n0n + row) * KDIM);
                #pragma unroll
                for (int i = 0; i < 8; ++i) R[p * 8 + i] = eg[sq + 8 * i];
            }
        }

        float acc[4][4];
        #pragma unroll
        for (int i = 0; i < 4; ++i)
            #pragma unroll
            for (int j = 0; j < 4; ++j) acc[i][j] = 0.f;

        #pragma unroll 4
        for (int kq = 0; kq < 64; ++kq) {
            const int zo = (kq ^ kz) << 2;
            const int eo = (kq ^ ke) << 2;
            float4 zq[4], eq[4];
            #pragma unroll
            for (int i = 0; i < 4; ++i) zq[i] = *(const float4*)(zb4 + (i << 8) + zo);
            #pragma unroll
            for (int j = 0; j < 4; ++j) eq[j] = *(const float4*)(eb4 + (j << 8) + eo);
            #pragma unroll
            for (int i = 0; i < 4; ++i)
                #pragma unroll
                for (int j = 0; j < 4; ++j) {
                    acc[i][j] = fmaf(zq[i].x, eq[j].x, acc[i][j]);
                    acc[i][j] = fmaf(zq[i].y, eq[j].y, acc[i][j]);
                    acc[i][j] = fmaf(zq[i].z, eq[j].z, acc[i][j]);
                    acc[i][j] = fmaf(zq[i].w, eq[j].w, acc[i][j]);
                }
        }

        const int n0 = nt * NT;
        #pragma unroll
        for (int j = 0; j < 4; ++j) {
            const int n = n0 + 4 * h + j;     // ascending n scan
            #pragma unroll
            for (int i = 0; i < 4; ++i) {
                const float d = z2r[i] - 2.f * acc[i][j];
                if (d < b1d[i]) {
                    b3d[i] = b2d[i]; n3[i] = n2[i];
                    b2d[i] = b1d[i]; n2[i] = n1[i];
                    b1d[i] = d;      n1[i] = n;
                } else if (d < b2d[i]) {
                    b3d[i] = b2d[i]; n3[i] = n2[i];
                    b2d[i] = d;      n2[i] = n;
                } else if (d < b3d[i]) {
                    b3d[i] = d;      n3[i] = n;
                }
            }
        }
    }

    __syncthreads();   // last compute done; es now dead -> overlay reductions

    #pragma unroll
    for (int i = 0; i < 4; ++i) {
        const int base = ((4 * g + i) * 16 + h) * 3;
        red_d[base + 0] = b1d[i]; red_n[base + 0] = n1[i];
        red_d[base + 1] = b2d[i]; red_n[base + 1] = n2[i];
        red_d[base + 2] = b3d[i]; red_n[base + 2] = n3[i];
    }
    __syncthreads();

    // ---- merge top-2 across 16 threads, lexicographic (d, n); flag + enumerate
    if (tid < MT) {
        float B1 = FLT_MAX, B2 = FLT_MAX;
        int   N1 = 0x7FFFFFFF;
        for (int t = 0; t < 16; ++t) {
            const int base = (tid * 16 + t) * 3;
            const float c1 = red_d[base + 0]; const int cn = red_n[base + 0];
            const float c2 = red_d[base + 1];
            if (c1 < B1 || (c1 == B1 && cn < N1)) {
                B2 = fminf(B1, c2); B1 = c1; N1 = cn;
            } else {
                B2 = fminf(B2, c1);
            }
        }
        best_s[tid] = B1; bestn_s[tid] = N1;
        if (B2 - B1 <= MARGIN) {
            const float thr = B1 + MARGIN;
            for (int t = 0; t < 16; ++t) {
                const int base = (tid * 16 + t) * 3;
                #pragma unroll
                for (int s = 0; s < 3; ++s) {
                    if (red_d[base + s] <= thr) {
                        const int pos = atomicAdd(&candcnt, 1);
                        if (pos < CANDCAP)
                            cand[pos] = (tid << 16) | red_n[base + s];
                    }
                }
            }
        }
    }
    __syncthreads();

    // ================= PASS B: exact fp64 grid values for candidates ========
    {
        const int C = min(candcnt, CANDCAP);
        for (int c = tid; c < C; c += 256) {
            const int rw = cand[c] >> 16, n = cand[c] & 0xFFFF;
            const float4* er = (const float4*)(emb + (size_t)n * KDIM);
            const int key = (rw >> 2) & 7;
            const float* zr = zT + (rw << 8);
            double dd = 0.0;
            for (int kq = 0; kq < 64; ++kq) {
                const float4 ev = er[kq];
                const float4 zv = *(const float4*)(zr + ((kq ^ key) << 2));
                dd = fma((double)zv.x, (double)ev.x, dd);
                dd = fma((double)zv.y, (double)ev.y, dd);
                dd = fma((double)zv.z, (double)ev.z, dd);
                dd = fma((double)zv.w, (double)ev.w, dd);
            }
            const float dg = z2s[rw] - 2.f * (float)dd;   // exact fp32-grid value
            const unsigned long long keyp =
                ((unsigned long long)__float_as_uint(dg) << 32)
                | (unsigned long long)(unsigned)n;
            atomicMin(&packed_s[rw], keyp);
        }
    }
    __syncthreads();

    // ---- final index per row
    if (tid < MT) {
        int n = bestn_s[tid];
        if (packed_s[tid] != ~0ull) n = (int)(packed_s[tid] & 0xFFFFFFFFull);
        idx_s[tid] = n;
        out[IDX_OFF + m0 + tid] = (float)n;
    }
    __syncthreads();

    // ---- gather emb[best] -> quantized + st (coalesced along hw)
    const int r  = tid & 63;
    const int c0 = tid >> 6;
    const float* erow = emb + (size_t)idx_s[r] * KDIM;
    const size_t obase = (size_t)nimg * 262144 + hw0 + r;
    for (int c = c0; c < KDIM; c += 4) {
        const float qv = erow[c];
        out[obase + (size_t)c * 1024] = qv;
        out[ST_OFF + obase + (size_t)c * 1024] = qv;
    }
}

extern "C" void kernel_launch(void* const* d_in, const int* in_sizes, int n_in,
                              void* d_out, int out_size, void* d_ws, size_t ws_size,
                              hipStream_t stream) {
    const float* zp   = (const float*)d_in[0];
    const float* embp = (const float*)d_in[1];
    float* outp = (float*)d_out;
    vq_kernel<<<MTOTAL / MT, 256, 0, stream>>>(zp, embp, outp);
}

// Round 4
// 192.582 us; speedup vs baseline: 19.6962x; 10.1953x over previous
//
#include <hip/hip_runtime.h>
#include <float.h>

// VQ-VAE codebook assignment via bf16 MFMA pass A + exact fp64 pass B.
// Pass A: D[code][zrow] = mfma_32x32x16_bf16(E_frag, Z_frag); per-lane top-3
// of acc with code packed into low-13 mantissa bits. Rows with merged
// B2-B1 <= MARGIN get exact fp64 dots -> fp32-grid lexicographic argmin.
// z: [16,256,32,32] f32; emb: [8192,256] f32
// out: [quantized 4194304][st 4194304][indices-as-float 16384]
// d_ws: emb as bf16 in MFMA-fragment order [256 grp][16 t][64 lane][8 bf16]

typedef short bf16x8 __attribute__((ext_vector_type(8)));
typedef float f32x16 __attribute__((ext_vector_type(16)));

#define KDIM 256
#define NCODES 8192
#define MTOTAL 16384
#define MT 64
#define ST_OFF 4194304
#define IDX_OFF 8388608
#define MARGIN 2e-4f     // bf16 d-err + pack-err + fp32 grid cell, with headroom
#define CANDCAP 1024

__device__ __forceinline__ unsigned short f2bf(float f) {  // RNE f32->bf16
    union { float f; unsigned u; } v; v.f = f;
    unsigned r = v.u + 0x7FFFu + ((v.u >> 16) & 1u);
    return (unsigned short)(r >> 16);
}
// zT fp32 swizzle (round-3 verified): rows accessed at stride 4 -> key=(row>>2)&7
__device__ __forceinline__ int swz_idx(int row, int k) {
    return (row << 8) + ((((k >> 2) ^ ((row >> 2) & 7)) << 2) | (k & 3));
}

// ---- pre-kernel: emb fp32 -> bf16 in A-fragment order -------------------
// frag F=(grp*16+t)*64+lane holds E[grp*32+(lane&31)][16t+4*(lane>>5)+{0..3}]
// then [... +8 +{0..3}]  (32x32x16 A-layout: m=l&31, k=4*(l>>5)+j (+8 hi-block))
__global__ void emb_pack(const float* __restrict__ emb,
                         unsigned short* __restrict__ ws) {
    const int F    = blockIdx.x * 256 + threadIdx.x;   // 262144 frags
    const int lane = F & 63;
    const int t    = (F >> 6) & 15;
    const int grp  = F >> 10;
    const int code = grp * 32 + (lane & 31);
    const int kb   = 16 * t + 4 * (lane >> 5);
    const float4 lo = *(const float4*)(emb + (size_t)code * KDIM + kb);
    const float4 hi = *(const float4*)(emb + (size_t)code * KDIM + kb + 8);
    uint4 o;
    o.x = (unsigned)f2bf(lo.x) | ((unsigned)f2bf(lo.y) << 16);
    o.y = (unsigned)f2bf(lo.z) | ((unsigned)f2bf(lo.w) << 16);
    o.z = (unsigned)f2bf(hi.x) | ((unsigned)f2bf(hi.y) << 16);
    o.w = (unsigned)f2bf(hi.z) | ((unsigned)f2bf(hi.w) << 16);
    *(uint4*)(ws + (size_t)F * 8) = o;
}

// ---- main kernel --------------------------------------------------------
__global__ __launch_bounds__(512, 2) void vq_mfma(
    const float* __restrict__ z, const float* __restrict__ emb,
    const unsigned short* __restrict__ ebf, float* __restrict__ out)
{
    __shared__ float  zT[MT * KDIM];          // 64 KB fp32, swizzled
    __shared__ double z2part[MT][8];
    __shared__ float  z2s[MT];
    __shared__ float  red_d[MT * 16 * 3];     // 16 lists/row x top-3
    __shared__ int    red_n[MT * 16 * 3];
    __shared__ float  best_s[MT];
    __shared__ int    bestn_s[MT];
    __shared__ unsigned long long packed_s[MT];
    __shared__ int    cand[CANDCAP];
    __shared__ int    candcnt;
    __shared__ int    idx_s[MT];

    const int tid  = threadIdx.x;
    const int lane = tid & 63;
    const int W    = tid >> 6;                // wave 0..7
    const int m0   = blockIdx.x * MT;
    const int nimg = m0 >> 10;
    const int hw0  = m0 & 1023;

    // stage z transposed: zT[r][k] = z[nimg, k, hw0+r] (swizzled, coalesced)
    {
        const float* zb = z + (size_t)nimg * (KDIM * 1024) + hw0 + lane;
        const int ks = W * 32;
        #pragma unroll 8
        for (int i = 0; i < 32; ++i) {
            const int k = ks + i;
            zT[swz_idx(lane, k)] = zb[(size_t)k * 1024];
        }
    }
    if (tid == 0) candcnt = 0;
    __syncthreads();

    // ||z||^2 partials, 8 threads/row, fp64 (per-row offset is argmin-invariant)
    {
        const int row = tid >> 3, ks = (tid & 7) << 5;
        double s = 0.0;
        for (int k = ks; k < ks + 32; ++k) {
            const double v = (double)zT[swz_idx(row, k)];
            s = fma(v, v, s);
        }
        z2part[row][tid & 7] = s;
    }
    __syncthreads();
    if (tid < MT) {
        double s = 0.0;
        #pragma unroll
        for (int p = 0; p < 8; ++p) s += z2part[tid][p];
        z2s[tid] = (float)s;
        packed_s[tid] = ~0ull;
    }

    // build z B-frags in registers (bf16): lane holds rows r0=lane&31, r1=r0+32
    // B-layout: n=l&31, k = 4*(l>>5)+j (+8 for hi block) per 16-k chain t
    const int r0 = lane & 31, r1 = 32 + r0;
    const int gq = lane >> 5;                 // k-offset selector
    bf16x8 zb0[16], zb1[16];
    {
        const int key0 = (r0 >> 2) & 7, key1 = (r1 >> 2) & 7;
        const float* zr0 = zT + (r0 << 8);
        const float* zr1 = zT + (r1 << 8);
        #pragma unroll
        for (int t = 0; t < 16; ++t) {
            const int qlo = 4 * t + gq, qhi = qlo + 2;
            float4 lo = *(const float4*)(zr0 + ((qlo ^ key0) << 2));
            float4 hi = *(const float4*)(zr0 + ((qhi ^ key0) << 2));
            bf16x8 v;
            v[0]=(short)f2bf(lo.x); v[1]=(short)f2bf(lo.y);
            v[2]=(short)f2bf(lo.z); v[3]=(short)f2bf(lo.w);
            v[4]=(short)f2bf(hi.x); v[5]=(short)f2bf(hi.y);
            v[6]=(short)f2bf(hi.z); v[7]=(short)f2bf(hi.w);
            zb0[t] = v;
            lo = *(const float4*)(zr1 + ((qlo ^ key1) << 2));
            hi = *(const float4*)(zr1 + ((qhi ^ key1) << 2));
            v[0]=(short)f2bf(lo.x); v[1]=(short)f2bf(lo.y);
            v[2]=(short)f2bf(lo.z); v[3]=(short)f2bf(lo.w);
            v[4]=(short)f2bf(hi.x); v[5]=(short)f2bf(hi.y);
            v[6]=(short)f2bf(hi.z); v[7]=(short)f2bf(hi.w);
            zb1[t] = v;
        }
    }
    __syncthreads();   // z2s ready; zT stable for pass B

    // ================= PASS A: MFMA sweep, no barriers =================
    // wave W covers codes [W*1024, W*1024+1024) as 32 groups of 32
    float s1a = -FLT_MAX, s2a = -FLT_MAX, s3a = -FLT_MAX;   // packed (acc|code)
    float s1b = -FLT_MAX, s2b = -FLT_MAX, s3b = -FLT_MAX;
    {
        const bf16x8* ap0 = reinterpret_cast<const bf16x8*>(ebf)
                            + ((size_t)W * 32 * 16 * 64 + lane);
        for (int g = 0; g < 32; ++g) {
            const bf16x8* ap = ap0 + (size_t)g * (16 * 64);
            f32x16 acc0, acc1;
            #pragma unroll
            for (int i = 0; i < 16; ++i) { acc0[i] = 0.f; acc1[i] = 0.f; }
            #pragma unroll
            for (int t = 0; t < 16; ++t) {
                const bf16x8 a = ap[t * 64];
                acc0 = __builtin_amdgcn_mfma_f32_32x32x16_bf16(a, zb0[t], acc0, 0, 0, 0);
                acc1 = __builtin_amdgcn_mfma_f32_32x32x16_bf16(a, zb1[t], acc1, 0, 0, 0);
            }
            // selection: D row index (code-in-group) = (r&3)+8*(r>>2)+4*(l>>5)
            const int cbase = (W * 32 + g) * 32 + 4 * gq;
            #pragma unroll
            for (int r = 0; r < 16; ++r) {
                const int code = cbase + (r & 3) + ((r >> 2) << 3);
                {   // pack code into low 13 mantissa bits; 5-op sorted insert
                    const float kk = __uint_as_float(
                        (__float_as_uint(acc0[r]) & 0xFFFFE000u) | (unsigned)code);
                    const float t1 = fminf(kk, s1a); s1a = fmaxf(kk, s1a);
                    const float t2 = fminf(t1, s2a); s2a = fmaxf(t1, s2a);
                    s3a = fmaxf(t2, s3a);
                }
                {
                    const float kk = __uint_as_float(
                        (__float_as_uint(acc1[r]) & 0xFFFFE000u) | (unsigned)code);
                    const float t1 = fminf(kk, s1b); s1b = fmaxf(kk, s1b);
                    const float t2 = fminf(t1, s2b); s2b = fmaxf(t1, s2b);
                    s3b = fmaxf(t2, s3b);
                }
            }
        }
    }

    // write per-lane top-3 lists (max acc -> min d, ascending)
    {
        const float z2r0 = z2s[r0], z2r1 = z2s[r1];
        const int L = (W << 1) | gq;
        const int b0 = (r0 * 16 + L) * 3, b1i = (r1 * 16 + L) * 3;
        red_d[b0+0] = z2r0 - 2.f*s1a; red_n[b0+0] = __float_as_uint(s1a) & 0x1FFF;
        red_d[b0+1] = z2r0 - 2.f*s2a; red_n[b0+1] = __float_as_uint(s2a) & 0x1FFF;
        red_d[b0+2] = z2r0 - 2.f*s3a; red_n[b0+2] = __float_as_uint(s3a) & 0x1FFF;
        red_d[b1i+0] = z2r1 - 2.f*s1b; red_n[b1i+0] = __float_as_uint(s1b) & 0x1FFF;
        red_d[b1i+1] = z2r1 - 2.f*s2b; red_n[b1i+1] = __float_as_uint(s2b) & 0x1FFF;
        red_d[b1i+2] = z2r1 - 2.f*s3b; red_n[b1i+2] = __float_as_uint(s3b) & 0x1FFF;
    }
    __syncthreads();

    // merge 16 lists/row, flag near-ties, enumerate candidates
    if (tid < MT) {
        float B1 = FLT_MAX, B2 = FLT_MAX;
        int   N1 = 0x7FFFFFFF;
        for (int t = 0; t < 16; ++t) {
            const int base = (tid * 16 + t) * 3;
            const float c1 = red_d[base + 0]; const int cn = red_n[base + 0];
            const float c2 = red_d[base + 1];
            if (c1 < B1 || (c1 == B1 && cn < N1)) { B2 = fminf(B1, c2); B1 = c1; N1 = cn; }
            else B2 = fminf(B2, c1);
        }
        best_s[tid] = B1; bestn_s[tid] = N1;
        if (B2 - B1 <= MARGIN) {
            const float thr = B1 + MARGIN;
            for (int t = 0; t < 16; ++t) {
                const int base = (tid * 16 + t) * 3;
                #pragma unroll
                for (int s = 0; s < 3; ++s) {
                    if (red_d[base + s] <= thr) {
                        const int pos = atomicAdd(&candcnt, 1);
                        if (pos < CANDCAP) cand[pos] = (tid << 16) | red_n[base + s];
                    }
                }
            }
        }
    }
    __syncthreads();

    // ================= PASS B: exact fp64 -> fp32-grid values ============
    {
        const int C = min(candcnt, CANDCAP);
        for (int c = tid; c < C; c += 512) {
            const int rw = cand[c] >> 16, n = cand[c] & 0xFFFF;
            const float4* er = (const float4*)(emb + (size_t)n * KDIM);
            const int key = (rw >> 2) & 7;
            const float* zr = zT + (rw << 8);
            double dd = 0.0;
            for (int kq = 0; kq < 64; ++kq) {
                const float4 ev = er[kq];
                const float4 zv = *(const float4*)(zr + ((kq ^ key) << 2));
                dd = fma((double)zv.x, (double)ev.x, dd);
                dd = fma((double)zv.y, (double)ev.y, dd);
                dd = fma((double)zv.z, (double)ev.z, dd);
                dd = fma((double)zv.w, (double)ev.w, dd);
            }
            const float dg = z2s[rw] - 2.f * (float)dd;   // exact fp32-grid value
            const unsigned long long keyp =
                ((unsigned long long)__float_as_uint(dg) << 32)
                | (unsigned long long)(unsigned)n;
            atomicMin(&packed_s[rw], keyp);               // lexicographic (d, n)
        }
    }
    __syncthreads();

    if (tid < MT) {
        int n = bestn_s[tid];
        if (packed_s[tid] != ~0ull) n = (int)(packed_s[tid] & 0xFFFFFFFFull);
        idx_s[tid] = n;
        out[IDX_OFF + m0 + tid] = (float)n;
    }
    __syncthreads();

    // gather emb[best] -> quantized + st (coalesced along hw)
    {
        const int r  = tid & 63;
        const int c0 = tid >> 6;
        const float* erow = emb + (size_t)idx_s[r] * KDIM;
        const size_t obase = (size_t)nimg * 262144 + hw0 + r;
        for (int c = c0; c < KDIM; c += 8) {
            const float qv = erow[c];
            out[obase + (size_t)c * 1024] = qv;
            out[ST_OFF + obase + (size_t)c * 1024] = qv;
        }
    }
}

extern "C" void kernel_launch(void* const* d_in, const int* in_sizes, int n_in,
                              void* d_out, int out_size, void* d_ws, size_t ws_size,
                              hipStream_t stream) {
    const float* zp   = (const float*)d_in[0];
    const float* embp = (const float*)d_in[1];
    float* outp = (float*)d_out;
    unsigned short* ws = (unsigned short*)d_ws;   // 4 MiB bf16 fragment buffer
    emb_pack<<<1024, 256, 0, stream>>>(embp, ws);
    vq_mfma<<<MTOTAL / MT, 512, 0, stream>>>(zp, embp, ws, outp);
}